// Round 4
// baseline (492.617 us; speedup 1.0000x reference)
//
#include <hip/hip_runtime.h>
#include <stdint.h>

typedef __attribute__((ext_vector_type(8))) short short8;
typedef __attribute__((ext_vector_type(4))) float f32x4;
typedef __attribute__((ext_vector_type(2))) unsigned int uint2v;

#define C0 228
#define C1 111
#define C2 51
#define KP 448           // padded channels: [0,256)=b0, [256,384)=b1, [384,448)=b2
#define RS 456           // LDS row stride (bf16 elems); 912 B = 57 quads -> +1 quad/row skew
#define NPIX 64
#define BUFE (NPIX * RS) // elems per LDS buffer
#define DYN_LDS (2 * BUFE * 2)  // 116736 bytes, double buffer

// ---- static (tile,ks) chunk schedule: 224 chunks = 8 waves x 28 slots ----
// ks 0..7 = K-block b0, 8..11 = b1, 12..13 = b2.
// waves 0-3 (class A): t0..t2 = b0 tiles 3w..3w+2, t3 = b1 tile 16+w
// waves 4-7 (class B): t0 = b0 tile 8+w, t1 = b1 tile 16+w, t2 = b2 tile 20+w
constexpr int A_KS[28] = {0,1,2,3,4,5,6,7,8,8,8,9,9,9,10,10,10,11,11,11,12,12,12,12,13,13,13,13};
constexpr int A_T [28] = {3,3,3,3,3,3,3,3,0,1,2,0,1,2, 0, 1, 2, 0, 1, 2, 0, 1, 2, 3, 0, 1, 2, 3};
constexpr int B_KS[28] = {0,0,1,1,2,2,3,3,4,4,5,5,6,6,7,7,8,8,9,9,10,10,11,11,12,12,13,13};
constexpr int B_T [28] = {1,2,1,2,1,2,1,2,1,2,1,2,1,2,1,2,0,2,0,2, 0, 2, 0, 2, 0, 1, 0, 1};

__host__ __device__ constexpr int tile_id(int w, int t) {
  return (w < 4) ? ((t < 3) ? (3 * w + t) : (16 + w))
                 : ((t == 0) ? (8 + w) : (t == 1) ? (16 + w) : (20 + w));
}

__device__ __forceinline__ unsigned short f2bf(float f) {
  unsigned u = __float_as_uint(f);
  u += 0x7FFFu + ((u >> 16) & 1u);          // RNE
  return (unsigned short)(u >> 16);
}
__device__ __forceinline__ float bf2f(unsigned v) {
  return __uint_as_float(v << 16);
}
__device__ __forceinline__ int out_chan(int c) {
  if (c < 228) return c;
  if (c < 256) return -1;
  if (c < 367) return 228 + (c - 256);
  if (c < 384) return -1;
  if (c < 435) return 339 + (c - 384);
  return -1;
}

// lgkm-only barrier: LDS ordering without draining outstanding global loads.
__device__ __forceinline__ void barrier_lgkm() {
  __builtin_amdgcn_sched_barrier(0);
  asm volatile("s_waitcnt lgkmcnt(0)" ::: "memory");
  __builtin_amdgcn_s_barrier();
  __builtin_amdgcn_sched_barrier(0);
}

// ---- prep: weights -> fragment-contiguous bf16 chunks (1KB each), + bias ----
__global__ void crf_prep(
    const float* __restrict__ w01, const float* __restrict__ w02,
    const float* __restrict__ w10, const float* __restrict__ w12,
    const float* __restrict__ w20, const float* __restrict__ w21,
    const float* __restrict__ b01, const float* __restrict__ b02,
    const float* __restrict__ b10, const float* __restrict__ b12,
    const float* __restrict__ b20, const float* __restrict__ b21,
    unsigned short* __restrict__ Wfrag, float* __restrict__ bbig) {
  int idx = blockIdx.x * 256 + threadIdx.x;     // 448 blocks -> 114688 = 224*512
  if (idx < KP) {
    float bv = 0.f;
    int c = idx;
    if (c < 228)                  bv = b10[c] + b20[c];
    else if (c >= 256 && c < 367) bv = b01[c - 256] + b21[c - 256];
    else if (c >= 384 && c < 435) bv = b02[c - 384] + b12[c - 384];
    bbig[idx] = bv;
  }
  if (idx >= 224 * 512) return;
  const int ch = idx >> 9;                      // chunk 0..223
  const int e  = idx & 511;
  const int w  = ch / 28;
  const int s  = ch - w * 28;
  const int ks = (w < 4) ? A_KS[s] : B_KS[s];
  const int tl = (w < 4) ? A_T[s]  : B_T[s];
  const int tile = tile_id(w, tl);
  const int lane = e >> 3, el = e & 7;
  const int m = tile * 16 + (lane & 15);
  const int k = ks * 32 + (lane >> 4) * 8 + el;

  int bm, lm, bk, lk, Ck;
  bool mr, kr;
  if (m < 256)      { bm = 0; lm = m;       mr = lm < C0; }
  else if (m < 384) { bm = 1; lm = m - 256; mr = lm < C1; }
  else              { bm = 2; lm = m - 384; mr = lm < C2; }
  if (k < 256)      { bk = 0; lk = k;       Ck = C0; kr = lk < C0; }
  else if (k < 384) { bk = 1; lk = k - 256; Ck = C1; kr = lk < C1; }
  else              { bk = 2; lk = k - 384; Ck = C2; kr = lk < C2; }
  float v = 0.f;
  if (bm != bk && mr && kr) {
    const float* wp;
    if (bk == 0)      wp = (bm == 1) ? w01 : w02;
    else if (bk == 1) wp = (bm == 0) ? w10 : w12;
    else              wp = (bm == 0) ? w20 : w21;
    v = wp[lm * Ck + lk];
  }
  Wfrag[idx] = f2bf(v);
}

// ---- stage helpers: issue loads early, consume late (async split) ----
template <int NG, int G0>
__device__ __forceinline__ void stage_load(int wave, int lane, int b, int pp,
    const float* __restrict__ x0, const float* __restrict__ x1,
    const float* __restrict__ x2, float (*dst)[8]) {
  #pragma unroll
  for (int gg = 0; gg < NG; ++gg) {
    const int cg = (wave + 8 * (G0 + gg)) * 8;
    #pragma unroll
    for (int cc = 0; cc < 8; ++cc) {
      const int c = cg + cc;
      float v = 0.f;
      if (c < 228)
        v = __builtin_nontemporal_load(x0 + (((size_t)(b * C0 + c)) << 16) + pp + lane);
      else if (c >= 256 && c < 367)
        v = __builtin_nontemporal_load(x1 + (((size_t)(b * C1 + (c - 256))) << 16) + pp + lane);
      else if (c >= 384 && c < 435)
        v = __builtin_nontemporal_load(x2 + (((size_t)(b * C2 + (c - 384))) << 16) + pp + lane);
      dst[gg][cc] = v;
    }
  }
}

template <int NG, int G0>
__device__ __forceinline__ void stage_write(int wave, int lane, float (*src)[8],
                                            unsigned short* __restrict__ nxt) {
  #pragma unroll
  for (int gg = 0; gg < NG; ++gg) {
    const int cg = (wave + 8 * (G0 + gg)) * 8;
    short8 pk;
    #pragma unroll
    for (int cc = 0; cc < 8; ++cc) pk[cc] = (short)f2bf(src[gg][cc]);
    *reinterpret_cast<short8*>(nxt + lane * RS + cg) = pk;
  }
}

// ---- K-loop: register weights x LDS h fragments ----
template <int CLS>
__device__ __forceinline__ void kloop(const unsigned short* __restrict__ cur,
                                      const short8 (&wreg)[28], f32x4 (&acc)[4][4],
                                      int l15, int lq) {
  short8 bq[4];
  #pragma unroll
  for (int s = 0; s < 28; ++s) {
    const int ks = CLS ? B_KS[s] : A_KS[s];
    const int t  = CLS ? B_T[s]  : A_T[s];
    const bool newks = (s == 0) || (ks != (CLS ? B_KS[s - 1] : A_KS[s - 1]));
    if (newks) {
      const int kcol = ks * 32 + (lq << 3);
      #pragma unroll
      for (int n = 0; n < 4; ++n)
        bq[n] = *reinterpret_cast<const short8*>(cur + (n * 16 + l15) * RS + kcol);
    }
    #pragma unroll
    for (int n = 0; n < 4; ++n)
      acc[t][n] = __builtin_amdgcn_mfma_f32_16x16x32_bf16(wreg[s], bq[n], acc[t][n], 0, 0, 0);
  }
}

// ---- main: 256 wgs x 512 thr, 1 wg/CU, 8 pixel-tiles each, dbuf LDS ----
__global__ __launch_bounds__(512, 2) void crf_main(
    const float* __restrict__ x0, const float* __restrict__ x1,
    const float* __restrict__ x2,
    const unsigned short* __restrict__ Wfrag,
    const float* __restrict__ bbig,
    const float* __restrict__ pa,
    float* __restrict__ out) {
  extern __shared__ unsigned short hbuf[];
  const int lane = threadIdx.x & 63;
  const int wave = threadIdx.x >> 6;
  const int l15 = lane & 15;
  const int lq = lane >> 4;
  const float apar = pa[0];

  // weights -> registers, once (28 contiguous 1KB chunks per wave)
  short8 wreg[28];
  {
    const unsigned short* wp = Wfrag + (((size_t)wave * 28) << 9) + lane * 8;
    #pragma unroll
    for (int s = 0; s < 28; ++s)
      wreg[s] = *reinterpret_cast<const short8*>(wp + (s << 9));
  }

  const int T0 = blockIdx.x * 8;            // 8 consecutive 64-px tiles
  const int b = (T0 >= 1024) ? 1 : 0;       // 128 wgs per image, never straddles
  const int ppbase = (T0 & 1023) << 6;

  // prologue: stage tile 0 into buffer 0
  {
    float sA[4][8], sB[3][8];
    stage_load<4, 0>(wave, lane, b, ppbase, x0, x1, x2, sA);
    stage_load<3, 4>(wave, lane, b, ppbase, x0, x1, x2, sB);
    stage_write<4, 0>(wave, lane, sA, hbuf);
    stage_write<3, 4>(wave, lane, sB, hbuf);
  }
  barrier_lgkm();

  for (int i = 0; i < 8; ++i) {
    unsigned short* cur = hbuf + (i & 1) * BUFE;
    unsigned short* nxt = hbuf + ((i + 1) & 1) * BUFE;
    const int pp0 = ppbase + (i << 6);
    const int pp1 = pp0 + 64;
    const bool more = (i < 7);

    // --- issue stage seg0 loads for tile i+1 (hide under iter0 K-loop) ---
    float s0[4][8];
    if (more) stage_load<4, 0>(wave, lane, b, pp1, x0, x1, x2, s0);

    // --- iter 0 ---
    f32x4 acc[4][4];
    #pragma unroll
    for (int t = 0; t < 4; ++t)
      #pragma unroll
      for (int n = 0; n < 4; ++n) acc[t][n] = (f32x4){0.f, 0.f, 0.f, 0.f};
    if (wave < 4) kloop<0>(cur, wreg, acc, l15, lq);
    else          kloop<1>(cur, wreg, acc, l15, lq);

    if (more) stage_write<4, 0>(wave, lane, s0, nxt);   // consume seg0 (vmcnt waits here)
    barrier_lgkm();   // iter0 reads of cur complete before h1 writeback

    // --- h1 = relu(h0 + prelu(binary + bias)) in place (own channels) ---
    #pragma unroll
    for (int t = 0; t < 4; ++t) {
      if (t == 3 && wave >= 4) continue;
      const int cb = tile_id(wave, t) * 16 + (lq << 2);
      const f32x4 bias = *reinterpret_cast<const f32x4*>(bbig + cb);
      #pragma unroll
      for (int n = 0; n < 4; ++n) {
        const int p = n * 16 + l15;
        uint2v ho = *reinterpret_cast<const uint2v*>(cur + p * RS + cb);
        const float hof[4] = {bf2f(ho[0] & 0xFFFFu), bf2f(ho[0] >> 16),
                              bf2f(ho[1] & 0xFFFFu), bf2f(ho[1] >> 16)};
        unsigned short nb[4];
        #pragma unroll
        for (int r = 0; r < 4; ++r) {
          float v = acc[t][n][r] + bias[r];
          float pr = (v >= 0.f) ? v : apar * v;
          nb[r] = f2bf(fmaxf(hof[r] + pr, 0.f));
        }
        uint2v pw;
        pw[0] = (unsigned)nb[0] | ((unsigned)nb[1] << 16);
        pw[1] = (unsigned)nb[2] | ((unsigned)nb[3] << 16);
        *reinterpret_cast<uint2v*>(cur + p * RS + cb) = pw;
      }
    }

    // --- issue stage seg1 loads for tile i+1 (hide under iter1 K-loop) ---
    float s1[3][8];
    if (more) stage_load<3, 4>(wave, lane, b, pp1, x0, x1, x2, s1);
    barrier_lgkm();   // h1 visible to all waves

    // --- iter 1 ---
    #pragma unroll
    for (int t = 0; t < 4; ++t)
      #pragma unroll
      for (int n = 0; n < 4; ++n) acc[t][n] = (f32x4){0.f, 0.f, 0.f, 0.f};
    if (wave < 4) kloop<0>(cur, wreg, acc, l15, lq);
    else          kloop<1>(cur, wreg, acc, l15, lq);

    // --- epilogue: out = relu(h1 + prelu(binary + bias)) -> global (nt) ---
    #pragma unroll
    for (int t = 0; t < 4; ++t) {
      if (t == 3 && wave >= 4) continue;
      const int cb = tile_id(wave, t) * 16 + (lq << 2);
      const f32x4 bias = *reinterpret_cast<const f32x4*>(bbig + cb);
      #pragma unroll
      for (int n = 0; n < 4; ++n) {
        const int p = n * 16 + l15;
        uint2v ho = *reinterpret_cast<const uint2v*>(cur + p * RS + cb);
        const float hof[4] = {bf2f(ho[0] & 0xFFFFu), bf2f(ho[0] >> 16),
                              bf2f(ho[1] & 0xFFFFu), bf2f(ho[1] >> 16)};
        #pragma unroll
        for (int r = 0; r < 4; ++r) {
          const int c = cb + r;
          const int o = out_chan(c);
          float v = acc[t][n][r] + bias[r];
          float pr = (v >= 0.f) ? v : apar * v;
          float hn = fmaxf(hof[r] + pr, 0.f);
          if (o >= 0)
            __builtin_nontemporal_store(
                hn, out + (((size_t)(b * 390 + o)) << 16) + pp0 + p);
        }
      }
    }

    if (more) stage_write<3, 4>(wave, lane, s1, nxt);   // consume seg1
    barrier_lgkm();   // nxt fully staged before next tile's iter0
  }
}

extern "C" void kernel_launch(void* const* d_in, const int* in_sizes, int n_in,
                              void* d_out, int out_size, void* d_ws, size_t ws_size,
                              hipStream_t stream) {
  const float* x0  = (const float*)d_in[0];
  const float* x1  = (const float*)d_in[1];
  const float* x2  = (const float*)d_in[2];
  const float* w01 = (const float*)d_in[3];
  const float* b01 = (const float*)d_in[4];
  const float* w02 = (const float*)d_in[5];
  const float* b02 = (const float*)d_in[6];
  const float* w10 = (const float*)d_in[7];
  const float* b10 = (const float*)d_in[8];
  const float* w12 = (const float*)d_in[9];
  const float* b12 = (const float*)d_in[10];
  const float* w20 = (const float*)d_in[11];
  const float* b20 = (const float*)d_in[12];
  const float* w21 = (const float*)d_in[13];
  const float* b21 = (const float*)d_in[14];
  const float* pa  = (const float*)d_in[15];

  unsigned short* Wfrag = (unsigned short*)d_ws;                  // 224*512*2 = 229376 B
  float* bbig = (float*)((char*)d_ws + 224 * 512 * 2);            // +1792 B

  hipFuncSetAttribute((const void*)crf_main,
                      hipFuncAttributeMaxDynamicSharedMemorySize, DYN_LDS);

  crf_prep<<<dim3(448), dim3(256), 0, stream>>>(
      w01, w02, w10, w12, w20, w21, b01, b02, b10, b12, b20, b21, Wfrag, bbig);
  crf_main<<<dim3(256), dim3(512), DYN_LDS, stream>>>(x0, x1, x2, Wfrag, bbig, pa,
                                                      (float*)d_out);
}